// Round 1
// baseline (632.108 us; speedup 1.0000x reference)
//
#include <hip/hip_runtime.h>
#include <hip/hip_bf16.h>

#define SEQ 4096
#define BATCH 2
#define HEADS 16
#define DHEAD 64
#define HID 1024

typedef unsigned short ushort_t;
typedef __attribute__((ext_vector_type(8))) short short8;
typedef __attribute__((ext_vector_type(4))) float f32x4;

__device__ __forceinline__ ushort_t f2b(float f) {
  unsigned u = __builtin_bit_cast(unsigned, f);
  unsigned r = 0x7fffu + ((u >> 16) & 1u);
  return (ushort_t)((u + r) >> 16);
}

__device__ __forceinline__ void gload16(const void* g, void* l) {
  __builtin_amdgcn_global_load_lds((const __attribute__((address_space(1))) void*)g,
                                   (__attribute__((address_space(3))) void*)l, 16, 0, 0);
}

__device__ __forceinline__ f32x4 mfma_bf16(short8 a, short8 b, f32x4 c) {
  return __builtin_amdgcn_mfma_f32_16x16x32_bf16(a, b, c, 0, 0, 0);
}

// ---------------- fp32 -> bf16 elementwise (vectorized) ----------------
__global__ void cvt_kernel(const float* __restrict__ in, ushort_t* __restrict__ out, int n4) {
  int i = blockIdx.x * blockDim.x + threadIdx.x;
  if (i >= n4) return;
  float4 v = reinterpret_cast<const float4*>(in)[i];
  ushort4 o;
  o.x = f2b(v.x); o.y = f2b(v.y); o.z = f2b(v.z); o.w = f2b(v.w);
  reinterpret_cast<ushort4*>(out)[i] = o;
}

// ---------------- transpose + convert: in[rows][cols] f32 -> out[cols][rows] bf16 ----------------
__global__ void transpose_cvt_kernel(const float* __restrict__ in, ushort_t* __restrict__ out,
                                     int rows, int cols) {
  __shared__ float tile[32][33];
  int tx = threadIdx.x & 31, ty = threadIdx.x >> 5;  // 256 threads: ty 0..7
  int r0 = blockIdx.y * 32, c0 = blockIdx.x * 32;
#pragma unroll
  for (int i = 0; i < 32; i += 8)
    tile[ty + i][tx] = in[(size_t)(r0 + ty + i) * cols + c0 + tx];
  __syncthreads();
#pragma unroll
  for (int i = 0; i < 32; i += 8)
    out[(size_t)(c0 + ty + i) * rows + r0 + tx] = f2b(tile[tx][ty + i]);
}

// ---------------- bf16 GEMM: C = A[M][K] * BT[N][K]^T ----------------
// MODE 0: scatter-write q/k/vT bf16.  MODE 1: write fp32 C.
template <int MODE>
__global__ __launch_bounds__(256, 2)
void gemm_kernel(const ushort_t* __restrict__ A, const ushort_t* __restrict__ BT,
                 int M, int N, int K,
                 ushort_t* __restrict__ qg, ushort_t* __restrict__ kg,
                 ushort_t* __restrict__ vTg, float* __restrict__ outf) {
  __shared__ ushort_t lA[128 * 64];
  __shared__ ushort_t lB[128 * 64];
  int tid = threadIdx.x;
  int lane = tid & 63, w = tid >> 6;
  int m0 = blockIdx.x * 128, n0 = blockIdx.y * 128;
  int wr = (w >> 1) * 64, wc = (w & 1) * 64;
  int lr = lane & 15, lg = lane >> 4;

  const f32x4 z4 = {0.f, 0.f, 0.f, 0.f};
  f32x4 acc[4][4];
#pragma unroll
  for (int m = 0; m < 4; ++m)
#pragma unroll
    for (int n = 0; n < 4; ++n) acc[m][n] = z4;

  int ktiles = K >> 6;
  for (int kt = 0; kt < ktiles; ++kt) {
    int k0 = kt << 6;
#pragma unroll
    for (int i = 0; i < 4; ++i) {
      int c = i * 256 + tid;
      int row = c >> 3, c8 = c & 7;
      gload16(A + (size_t)(m0 + row) * K + k0 + c8 * 8, lA + c * 8);
    }
#pragma unroll
    for (int i = 0; i < 4; ++i) {
      int c = i * 256 + tid;
      int row = c >> 3, c8 = c & 7;
      gload16(BT + (size_t)(n0 + row) * K + k0 + c8 * 8, lB + c * 8);
    }
    __syncthreads();
#pragma unroll
    for (int kk = 0; kk < 2; ++kk) {
      short8 a[4], b[4];
#pragma unroll
      for (int m = 0; m < 4; ++m)
        a[m] = *(const short8*)(lA + (wr + m * 16 + lr) * 64 + kk * 32 + lg * 8);
#pragma unroll
      for (int n = 0; n < 4; ++n)
        b[n] = *(const short8*)(lB + (wc + n * 16 + lr) * 64 + kk * 32 + lg * 8);
#pragma unroll
      for (int m = 0; m < 4; ++m)
#pragma unroll
        for (int n = 0; n < 4; ++n)
          acc[m][n] = mfma_bf16(a[m], b[n], acc[m][n]);
    }
    __syncthreads();
  }

#pragma unroll
  for (int m = 0; m < 4; ++m)
#pragma unroll
    for (int n = 0; n < 4; ++n)
#pragma unroll
      for (int r = 0; r < 4; ++r) {
        int i = m0 + wr + m * 16 + lg * 4 + r;
        int j = n0 + wc + n * 16 + lr;
        float v = acc[m][n][r];
        if (MODE == 0) {
          int mat = j >> 10, rem = j & 1023;
          int h = rem >> 6, d = rem & 63;
          int b = i >> 12, s = i & 4095;
          int bh = b * HEADS + h;
          ushort_t val = f2b(v);
          if (mat == 0)      qg[((size_t)bh * SEQ + s) * DHEAD + d] = val;
          else if (mat == 1) kg[((size_t)bh * SEQ + s) * DHEAD + d] = val;
          else               vTg[((size_t)bh * DHEAD + d) * SEQ + s] = val;
        } else {
          outf[(size_t)i * N + j] = v;
        }
      }
}

// ---------------- flash attention: per block one (b,h, 128-row q tile) ----------------
__global__ __launch_bounds__(256, 2)
void attn_kernel(const ushort_t* __restrict__ qg, const ushort_t* __restrict__ kg,
                 const ushort_t* __restrict__ vTg, ushort_t* __restrict__ og) {
  __shared__ ushort_t lQ[128 * 64];
  __shared__ ushort_t lK[128 * 64];
  __shared__ ushort_t lV[64 * 128];
  __shared__ ushort_t lP[128 * 128];

  int bid = blockIdx.x;
  int qt = 31 - (bid & 31);  // heavy tiles first
  int bh = bid >> 5;
  int q0 = qt * 128;
  const ushort_t* Q = qg + (size_t)bh * SEQ * DHEAD;
  const ushort_t* Kp = kg + (size_t)bh * SEQ * DHEAD;
  const ushort_t* Vt = vTg + (size_t)bh * DHEAD * SEQ;

  int tid = threadIdx.x, lane = tid & 63, w = tid >> 6;
  int lr = lane & 15, lg = lane >> 4;

#pragma unroll
  for (int i = 0; i < 4; ++i) {
    int c = i * 256 + tid;
    gload16(Q + q0 * DHEAD + c * 8, lQ + c * 8);
  }

  const f32x4 z4 = {0.f, 0.f, 0.f, 0.f};
  float mrow[2][4], lsum[2][4];
  f32x4 o[2][4];
#pragma unroll
  for (int m = 0; m < 2; ++m)
#pragma unroll
    for (int r = 0; r < 4; ++r) { mrow[m][r] = -1e30f; lsum[m][r] = 0.f; }
#pragma unroll
  for (int m = 0; m < 2; ++m)
#pragma unroll
    for (int n = 0; n < 4; ++n) o[m][n] = z4;

  for (int jt = 0; jt <= qt; ++jt) {
    int j0 = jt * 128;
#pragma unroll
    for (int i = 0; i < 4; ++i) {
      int c = i * 256 + tid;
      gload16(Kp + j0 * DHEAD + c * 8, lK + c * 8);
    }
#pragma unroll
    for (int i = 0; i < 4; ++i) {
      int c = i * 256 + tid;
      int d = c >> 4, c8 = c & 15;
      gload16(Vt + (size_t)d * SEQ + j0 + c8 * 8, lV + c * 8);
    }
    __syncthreads();

    // S = Q K^T
    f32x4 s[2][8];
#pragma unroll
    for (int m = 0; m < 2; ++m)
#pragma unroll
      for (int n = 0; n < 8; ++n) s[m][n] = z4;
#pragma unroll
    for (int kk = 0; kk < 2; ++kk) {
      short8 a[2];
#pragma unroll
      for (int m = 0; m < 2; ++m)
        a[m] = *(const short8*)(lQ + (w * 32 + m * 16 + lr) * 64 + kk * 32 + lg * 8);
#pragma unroll
      for (int nt = 0; nt < 8; ++nt) {
        short8 b = *(const short8*)(lK + (nt * 16 + lr) * 64 + kk * 32 + lg * 8);
#pragma unroll
        for (int m = 0; m < 2; ++m) s[m][nt] = mfma_bf16(a[m], b, s[m][nt]);
      }
    }

    // scale + causal mask
    bool diag = (jt == qt);
#pragma unroll
    for (int m = 0; m < 2; ++m)
#pragma unroll
      for (int nt = 0; nt < 8; ++nt)
#pragma unroll
        for (int r = 0; r < 4; ++r) {
          float v = s[m][nt][r] * 0.125f;
          if (diag && (j0 + nt * 16 + lr) > (q0 + w * 32 + m * 16 + lg * 4 + r)) v = -1e30f;
          s[m][nt][r] = v;
        }

    // online softmax (per row: 4 groups x 4 regs = 16 rows per m-tile)
#pragma unroll
    for (int m = 0; m < 2; ++m)
#pragma unroll
      for (int r = 0; r < 4; ++r) {
        float mx = s[m][0][r];
#pragma unroll
        for (int nt = 1; nt < 8; ++nt) mx = fmaxf(mx, s[m][nt][r]);
        mx = fmaxf(mx, __shfl_xor(mx, 1));
        mx = fmaxf(mx, __shfl_xor(mx, 2));
        mx = fmaxf(mx, __shfl_xor(mx, 4));
        mx = fmaxf(mx, __shfl_xor(mx, 8));
        float mo = mrow[m][r];
        float mn = fmaxf(mo, mx);
        float al = __expf(mo - mn);
        mrow[m][r] = mn;
        float rs = 0.f;
#pragma unroll
        for (int nt = 0; nt < 8; ++nt) {
          float p = __expf(s[m][nt][r] - mn);
          s[m][nt][r] = p;
          rs += p;
        }
        rs += __shfl_xor(rs, 1);
        rs += __shfl_xor(rs, 2);
        rs += __shfl_xor(rs, 4);
        rs += __shfl_xor(rs, 8);
        lsum[m][r] = lsum[m][r] * al + rs;
#pragma unroll
        for (int nd = 0; nd < 4; ++nd) o[m][nd][r] *= al;
      }

    // P -> LDS (bf16)
#pragma unroll
    for (int m = 0; m < 2; ++m)
#pragma unroll
      for (int nt = 0; nt < 8; ++nt)
#pragma unroll
        for (int r = 0; r < 4; ++r)
          lP[(w * 32 + m * 16 + lg * 4 + r) * 128 + nt * 16 + lr] = f2b(s[m][nt][r]);
    __syncthreads();

    // O += P V
#pragma unroll
    for (int kk = 0; kk < 4; ++kk) {
      short8 a[2];
#pragma unroll
      for (int m = 0; m < 2; ++m)
        a[m] = *(const short8*)(lP + (w * 32 + m * 16 + lr) * 128 + kk * 32 + lg * 8);
#pragma unroll
      for (int nd = 0; nd < 4; ++nd) {
        short8 b = *(const short8*)(lV + (nd * 16 + lr) * 128 + kk * 32 + lg * 8);
#pragma unroll
        for (int m = 0; m < 2; ++m) o[m][nd] = mfma_bf16(a[m], b, o[m][nd]);
      }
    }
    __syncthreads();
  }

  // epilogue: O /= l, write bf16 to [B][S][H*D]
  int b = bh >> 4, h = bh & 15;
#pragma unroll
  for (int m = 0; m < 2; ++m)
#pragma unroll
    for (int nd = 0; nd < 4; ++nd)
#pragma unroll
      for (int r = 0; r < 4; ++r) {
        int srow = q0 + w * 32 + m * 16 + lg * 4 + r;
        int col = h * 64 + nd * 16 + lr;
        float val = o[m][nd][r] / lsum[m][r];
        og[((size_t)b * SEQ + srow) * HID + col] = f2b(val);
      }
}

extern "C" void kernel_launch(void* const* d_in, const int* in_sizes, int n_in,
                              void* d_out, int out_size, void* d_ws, size_t ws_size,
                              hipStream_t stream) {
  const float* x = (const float*)d_in[0];
  const float* wqkv = (const float*)d_in[1];
  const float* wout = (const float*)d_in[2];
  float* out = (float*)d_out;

  if (ws_size < 75497472u) return;  // need 75.5 MB scratch

  char* ws = (char*)d_ws;
  ushort_t* xb    = (ushort_t*)(ws);               // 8192x1024 bf16 (reused as attn out)
  ushort_t* wqkvT = (ushort_t*)(ws + 16777216);    // 3072x1024
  ushort_t* woutT = (ushort_t*)(ws + 23068672);    // 1024x1024
  ushort_t* qgb   = (ushort_t*)(ws + 25165824);    // [32][4096][64]
  ushort_t* kgb   = (ushort_t*)(ws + 41943040);    // [32][4096][64]
  ushort_t* vTb   = (ushort_t*)(ws + 58720256);    // [32][64][4096]
  ushort_t* ob    = xb;

  cvt_kernel<<<dim3(8192), dim3(256), 0, stream>>>(x, xb, 2097152);
  transpose_cvt_kernel<<<dim3(96, 32), dim3(256), 0, stream>>>(wqkv, wqkvT, 1024, 3072);
  transpose_cvt_kernel<<<dim3(32, 32), dim3(256), 0, stream>>>(wout, woutT, 1024, 1024);
  gemm_kernel<0><<<dim3(64, 24), dim3(256), 0, stream>>>(xb, wqkvT, 8192, 3072, 1024,
                                                         qgb, kgb, vTb, nullptr);
  attn_kernel<<<dim3(1024), dim3(256), 0, stream>>>(qgb, kgb, vTb, ob);
  gemm_kernel<1><<<dim3(64, 8), dim3(256), 0, stream>>>(ob, woutT, 8192, 1024, 1024,
                                                        nullptr, nullptr, nullptr, out);
}